// Round 1
// baseline (278.822 us; speedup 1.0000x reference)
//
#include <hip/hip_runtime.h>
#include <hip/hip_bf16.h>

// ---------------- problem constants ----------------
#define E_    8
#define TT    4096      // tokens = B*S
#define DD    512
#define HH    2048
#define CAP   1075      // round(2*4096*1.05/8)
#define MPAD  1152      // 9 * 128, padded rows per expert
#define MT    9         // M tiles per expert

typedef __bf16 bf16_t;
typedef bf16_t bf16x8 __attribute__((ext_vector_type(8)));
typedef float  f32x4  __attribute__((ext_vector_type(4)));

__device__ __forceinline__ bf16_t tobf(float f) { return (bf16_t)f; }  // fptrunc, RNE

// ---------------- workspace layout (bytes) ----------------
// hdr: imp[8] f32 @0, kept[8] i32 @64
#define OFF_TOPI  256u
#define OFF_TOPG  (OFF_TOPI + 4096u*2u*4u)            // 33024
#define OFF_ETOK  (OFF_TOPG + 4096u*2u*4u)            // 65792
#define OFF_EWT   (OFF_ETOK + 8u*1152u*4u)            // 102656
#define OFF_XG    (OFF_EWT  + 8u*1152u*4u)            // 139520 (16B aligned)
#define XG_BYTES  (8u*1152u*512u*2u)                  // 9,437,184
#define OFF_W1T   (OFF_XG + XG_BYTES)
#define W1T_BYTES (8u*512u*2048u*2u)                  // 16,777,216
#define OFF_W2T   (OFF_W1T + W1T_BYTES)
#define W2T_BYTES (8u*2048u*512u*2u)                  // 16,777,216
#define OFF_H     (OFF_W2T + W2T_BYTES)
#define H_BYTES   (8u*1152u*2048u*2u)                 // 37,748,736
// total ~80.9 MB

// ---------------- router: logits, softmax, top-2, imp ----------------
__global__ __launch_bounds__(256) void router_kernel(
    const float* __restrict__ x, const float* __restrict__ gw,
    float* __restrict__ imp, int* __restrict__ top_i, float* __restrict__ top_g) {
  const int tid = threadIdx.x;
  const int wid = tid >> 6, lane = tid & 63;
  const int t = blockIdx.x * 4 + wid;

  float p[E_];
#pragma unroll
  for (int e = 0; e < E_; ++e) p[e] = 0.f;
  const float* xr = x + (size_t)t * DD;
#pragma unroll
  for (int it = 0; it < DD / 64; ++it) {
    const int d = it * 64 + lane;
    const float xv = xr[d];
#pragma unroll
    for (int e = 0; e < E_; ++e) p[e] += xv * gw[e * DD + d];
  }
#pragma unroll
  for (int off = 32; off > 0; off >>= 1) {
#pragma unroll
    for (int e = 0; e < E_; ++e) p[e] += __shfl_down(p[e], off);
  }

  __shared__ float simp[4][E_];
  if (lane == 0) {
    float mx = p[0];
#pragma unroll
    for (int e = 1; e < E_; ++e) mx = fmaxf(mx, p[e]);
    float g[E_]; float s = 0.f;
#pragma unroll
    for (int e = 0; e < E_; ++e) { g[e] = expf(p[e] - mx); s += g[e]; }
    const float inv = 1.f / s;
#pragma unroll
    for (int e = 0; e < E_; ++e) { g[e] *= inv; simp[wid][e] = g[e]; }
    // top-2, ties -> lowest index (matches jax.lax.top_k)
    int i0 = 0;
#pragma unroll
    for (int e = 1; e < E_; ++e) if (g[e] > g[i0]) i0 = e;
    int i1 = (i0 == 0) ? 1 : 0;
#pragma unroll
    for (int e = 0; e < E_; ++e) if (e != i0 && g[e] > g[i1]) i1 = e;
    top_i[t * 2 + 0] = i0;  top_i[t * 2 + 1] = i1;
    top_g[t * 2 + 0] = g[i0]; top_g[t * 2 + 1] = g[i1];
  }
  __syncthreads();
  if (tid < E_) {
    const float s = simp[0][tid] + simp[1][tid] + simp[2][tid] + simp[3][tid];
    atomicAdd(&imp[tid], s);
  }
}

// ---------------- capacity: slot-major exact cumsum + dispatch + scalars -------
__global__ __launch_bounds__(1024) void capacity_kernel(
    const int* __restrict__ top_i, const float* __restrict__ top_g,
    const float* __restrict__ imp, int* __restrict__ etok, float* __restrict__ ewt,
    int* __restrict__ kept, float* __restrict__ scal) {
  __shared__ int sc[1024 * E_];
  __shared__ int stot[E_];
  const int tid = threadIdx.x;

  int eidx[8];
#pragma unroll
  for (int q = 0; q < 8; ++q) {
    const int j = tid * 8 + q;          // slot-major: j = k*T + t
    const int k = j >> 12, t = j & (TT - 1);
    eidx[q] = top_i[t * 2 + k];
  }
  int cnt[E_], val[E_];
#pragma unroll
  for (int e = 0; e < E_; ++e) cnt[e] = 0;
#pragma unroll
  for (int q = 0; q < 8; ++q) cnt[eidx[q]]++;
#pragma unroll
  for (int e = 0; e < E_; ++e) val[e] = cnt[e];

  for (int off = 1; off < 1024; off <<= 1) {
#pragma unroll
    for (int e = 0; e < E_; ++e) sc[tid * E_ + e] = val[e];
    __syncthreads();
    if (tid >= off) {
#pragma unroll
      for (int e = 0; e < E_; ++e) val[e] += sc[(tid - off) * E_ + e];
    }
    __syncthreads();
  }
  if (tid == 1023) {
#pragma unroll
    for (int e = 0; e < E_; ++e) stot[e] = val[e];
  }
  int run[E_];
#pragma unroll
  for (int e = 0; e < E_; ++e) run[e] = val[e] - cnt[e];  // exclusive base
#pragma unroll
  for (int q = 0; q < 8; ++q) {
    const int e = eidx[q];
    const int pos = run[e]++;           // counts ALL earlier same-expert entries
    if (pos < CAP) {
      const int j = tid * 8 + q;
      const int k = j >> 12, t = j & (TT - 1);
      etok[e * MPAD + pos] = t;
      ewt[e * MPAD + pos] = top_g[t * 2 + k];
    }
  }
  __syncthreads();
  if (tid == 0) {
    float tpe[E_], mt = 0.f;
#pragma unroll
    for (int e = 0; e < E_; ++e) {
      const int kk = stot[e] < CAP ? stot[e] : CAP;
      kept[e] = kk; tpe[e] = (float)kk; mt += tpe[e];
    }
    mt *= (1.f / E_);
    float vt = 0.f;
#pragma unroll
    for (int e = 0; e < E_; ++e) { const float d = tpe[e] - mt; vt += d * d; }
    vt *= (1.f / E_);
    const float ll = vt / ((mt + 1e-6f) * (mt + 1e-6f));

    float iv[E_], mi = 0.f;
#pragma unroll
    for (int e = 0; e < E_; ++e) { iv[e] = imp[e]; mi += iv[e]; }
    mi *= (1.f / E_);
    float vi = 0.f;
#pragma unroll
    for (int e = 0; e < E_; ++e) { const float d = iv[e] - mi; vi += d * d; }
    vi *= (1.f / E_);
    const float il = vi / ((mi + 1e-6f) * (mi + 1e-6f));

    scal[0] = 0.5f * (il + ll);   // l_aux
    scal[1] = ll;                 // l_load
  }
}

// ---------------- gather x rows -> bf16 per-expert buffers ----------------
__global__ __launch_bounds__(64) void gather_kernel(
    const float* __restrict__ x, const int* __restrict__ etok,
    const int* __restrict__ kept, bf16_t* __restrict__ Xg) {
  const int e = blockIdx.y, m = blockIdx.x, lane = threadIdx.x;
  if (m >= kept[e]) return;             // padding rows stay zero (pre-memset)
  const int t = etok[e * MPAD + m];
  const float* src = x + (size_t)t * DD + lane * 8;
  const float4 a = *(const float4*)src;
  const float4 b = *(const float4*)(src + 4);
  bf16_t tmp[8] = {tobf(a.x), tobf(a.y), tobf(a.z), tobf(a.w),
                   tobf(b.x), tobf(b.y), tobf(b.z), tobf(b.w)};
  *(bf16x8*)(Xg + ((size_t)e * MPAD + m) * DD + lane * 8) = *(const bf16x8*)tmp;
}

// ---------------- weight transpose+cast: [E][R][C] f32 -> [E][C][R] bf16 ------
__global__ __launch_bounds__(256) void transpose_kernel(
    const float* __restrict__ in, bf16_t* __restrict__ outp, int R, int C) {
  __shared__ float tile[32][33];
  const int e = blockIdx.z;
  const int r0 = blockIdx.y * 32, c0 = blockIdx.x * 32;
  const int tx = threadIdx.x, ty = threadIdx.y;   // (32, 8)
  const float* ip = in + (size_t)e * R * C;
  bf16_t* op = outp + (size_t)e * R * C;
#pragma unroll
  for (int i = 0; i < 4; ++i)
    tile[ty + i * 8][tx] = ip[(size_t)(r0 + ty + i * 8) * C + c0 + tx];
  __syncthreads();
#pragma unroll
  for (int i = 0; i < 4; ++i)
    op[(size_t)(c0 + ty + i * 8) * R + r0 + tx] = tobf(tile[tx][ty + i * 8]);
}

// ---------------- TN GEMM core: C[128,128] tile, BK=64, m97-style ----------
// A: [rows][K] bf16 (row-major), B: [cols][K] bf16 (pre-transposed weights)
template <int K>
__device__ __forceinline__ void gemm_core(
    const bf16_t* __restrict__ A, const bf16_t* __restrict__ B,
    bf16_t* As, bf16_t* Bs, f32x4 acc[4][4]) {
  const int tid = threadIdx.x;
  const int wave = tid >> 6, lane = tid & 63;
  const int r8 = lane >> 3, c8 = (lane & 7) * 8;
  const bf16_t* ga = A + (size_t)(wave * 32 + r8) * K + c8;
  const bf16_t* gb = B + (size_t)(wave * 32 + r8) * K + c8;
  const int mw = (wave >> 1) * 64, nw = (wave & 1) * 64;
  const int l15 = lane & 15, quad = lane >> 4;

  for (int k0 = 0; k0 < K; k0 += 64) {
    __syncthreads();   // protect LDS from overwrite while prior chunk computes
#pragma unroll
    for (int p = 0; p < 4; ++p) {
      __builtin_amdgcn_global_load_lds(
          (const __attribute__((address_space(1))) void*)(ga + (size_t)p * 8 * K + k0),
          (__attribute__((address_space(3))) void*)(As + (wave * 32 + p * 8) * 64),
          16, 0, 0);
    }
#pragma unroll
    for (int p = 0; p < 4; ++p) {
      __builtin_amdgcn_global_load_lds(
          (const __attribute__((address_space(1))) void*)(gb + (size_t)p * 8 * K + k0),
          (__attribute__((address_space(3))) void*)(Bs + (wave * 32 + p * 8) * 64),
          16, 0, 0);
    }
    __syncthreads();   // drains vmcnt before compute
#pragma unroll
    for (int ks = 0; ks < 2; ++ks) {
      bf16x8 af[4], bfr[4];
#pragma unroll
      for (int i = 0; i < 4; ++i)
        af[i] = *(const bf16x8*)(As + (mw + i * 16 + l15) * 64 + ks * 32 + quad * 8);
#pragma unroll
      for (int j = 0; j < 4; ++j)
        bfr[j] = *(const bf16x8*)(Bs + (nw + j * 16 + l15) * 64 + ks * 32 + quad * 8);
#pragma unroll
      for (int i = 0; i < 4; ++i)
#pragma unroll
        for (int j = 0; j < 4; ++j)
          acc[i][j] = __builtin_amdgcn_mfma_f32_16x16x32_bf16(af[i], bfr[j], acc[i][j], 0, 0, 0);
    }
  }
}

// ---------------- GEMM1: H = gelu(Xg @ W1 + b1), bf16 out ----------------
__global__ __launch_bounds__(256, 2) void gemm1_kernel(
    const bf16_t* __restrict__ Xg, const bf16_t* __restrict__ W1t,
    const float* __restrict__ b1, bf16_t* __restrict__ Hbuf) {
  __shared__ __align__(16) bf16_t As[128 * 64];
  __shared__ __align__(16) bf16_t Bs[128 * 64];
  const int e = blockIdx.z, tileM = blockIdx.y, tileN = blockIdx.x;
  const bf16_t* A = Xg + ((size_t)e * MPAD + tileM * 128) * DD;
  const bf16_t* B = W1t + ((size_t)e * HH + tileN * 128) * DD;
  f32x4 acc[4][4];
  const f32x4 z = {0.f, 0.f, 0.f, 0.f};
#pragma unroll
  for (int i = 0; i < 4; ++i)
#pragma unroll
    for (int j = 0; j < 4; ++j) acc[i][j] = z;
  gemm_core<DD>(A, B, As, Bs, acc);

  const int tid = threadIdx.x, wave = tid >> 6, lane = tid & 63;
  const int mw = (wave >> 1) * 64, nw = (wave & 1) * 64;
  const int l15 = lane & 15, quad = lane >> 4;
#pragma unroll
  for (int i = 0; i < 4; ++i) {
    const int mbase = tileM * 128 + mw + i * 16 + quad * 4;
#pragma unroll
    for (int j = 0; j < 4; ++j) {
      const int n = tileN * 128 + nw + j * 16 + l15;
      const float bias = b1[e * HH + n];
#pragma unroll
      for (int r = 0; r < 4; ++r) {
        float v = acc[i][j][r] + bias;
        v = 0.5f * v * (1.f + erff(v * 0.70710678118654752f));  // exact gelu
        Hbuf[((size_t)e * MPAD + mbase + r) * HH + n] = tobf(v);
      }
    }
  }
}

// ---------------- GEMM2: y = H @ W2 + b2, scatter-combine via atomicAdd -------
__global__ __launch_bounds__(256, 2) void gemm2_kernel(
    const bf16_t* __restrict__ Hbuf, const bf16_t* __restrict__ W2t,
    const float* __restrict__ b2, const int* __restrict__ etok,
    const float* __restrict__ ewt, const int* __restrict__ kept,
    float* __restrict__ out) {
  __shared__ __align__(16) bf16_t As[128 * 64];
  __shared__ __align__(16) bf16_t Bs[128 * 64];
  const int e = blockIdx.z, tileM = blockIdx.y, tileN = blockIdx.x;
  const bf16_t* A = Hbuf + ((size_t)e * MPAD + tileM * 128) * HH;
  const bf16_t* B = W2t + ((size_t)e * DD + tileN * 128) * HH;
  f32x4 acc[4][4];
  const f32x4 z = {0.f, 0.f, 0.f, 0.f};
#pragma unroll
  for (int i = 0; i < 4; ++i)
#pragma unroll
    for (int j = 0; j < 4; ++j) acc[i][j] = z;
  gemm_core<HH>(A, B, As, Bs, acc);

  const int tid = threadIdx.x, wave = tid >> 6, lane = tid & 63;
  const int mw = (wave >> 1) * 64, nw = (wave & 1) * 64;
  const int l15 = lane & 15, quad = lane >> 4;
  const int nk = kept[e];
#pragma unroll
  for (int i = 0; i < 4; ++i) {
#pragma unroll
    for (int r = 0; r < 4; ++r) {
      const int m = tileM * 128 + mw + i * 16 + quad * 4 + r;
      if (m < nk) {
        const int t = etok[e * MPAD + m];
        const float g = ewt[e * MPAD + m];
        float* orow = out + (size_t)t * DD;
#pragma unroll
        for (int j = 0; j < 4; ++j) {
          const int n = tileN * 128 + nw + j * 16 + l15;
          atomicAdd(orow + n, g * (acc[i][j][r] + b2[e * DD + n]));
        }
      }
    }
  }
}

// ---------------- launch ----------------
extern "C" void kernel_launch(void* const* d_in, const int* in_sizes, int n_in,
                              void* d_out, int out_size, void* d_ws, size_t ws_size,
                              hipStream_t stream) {
  const float* x      = (const float*)d_in[0];
  const float* gate_w = (const float*)d_in[1];
  const float* fc1_w  = (const float*)d_in[2];
  const float* fc1_b  = (const float*)d_in[3];
  const float* fc2_w  = (const float*)d_in[4];
  const float* fc2_b  = (const float*)d_in[5];
  float* out = (float*)d_out;

  char* ws = (char*)d_ws;
  float*  imp   = (float*)(ws + 0);
  int*    kept  = (int*)(ws + 64);
  int*    top_i = (int*)(ws + OFF_TOPI);
  float*  top_g = (float*)(ws + OFF_TOPG);
  int*    etok  = (int*)(ws + OFF_ETOK);
  float*  ewt   = (float*)(ws + OFF_EWT);
  bf16_t* Xg    = (bf16_t*)(ws + OFF_XG);
  bf16_t* W1t   = (bf16_t*)(ws + OFF_W1T);
  bf16_t* W2t   = (bf16_t*)(ws + OFF_W2T);
  bf16_t* Hbuf  = (bf16_t*)(ws + OFF_H);
  // total ws need ~81 MB

  hipMemsetAsync(ws, 0, 256, stream);                          // imp + kept
  hipMemsetAsync(Xg, 0, XG_BYTES, stream);                     // zero row padding
  hipMemsetAsync(d_out, 0, (size_t)out_size * 4, stream);      // atomic combine base

  router_kernel<<<TT / 4, 256, 0, stream>>>(x, gate_w, imp, top_i, top_g);
  capacity_kernel<<<1, 1024, 0, stream>>>(top_i, top_g, imp, etok, ewt, kept,
                                          out + (size_t)TT * DD);
  gather_kernel<<<dim3(MPAD, E_), 64, 0, stream>>>(x, etok, kept, Xg);
  // fc1_w [E][512][2048] -> W1t [E][2048][512]
  transpose_kernel<<<dim3(HH / 32, DD / 32, E_), dim3(32, 8), 0, stream>>>(fc1_w, W1t, DD, HH);
  // fc2_w [E][2048][512] -> W2t [E][512][2048]
  transpose_kernel<<<dim3(DD / 32, HH / 32, E_), dim3(32, 8), 0, stream>>>(fc2_w, W2t, HH, DD);

  gemm1_kernel<<<dim3(HH / 128, MT, E_), 256, 0, stream>>>(Xg, W1t, fc1_b, Hbuf);
  gemm2_kernel<<<dim3(DD / 128, MT, E_), 256, 0, stream>>>(Hbuf, W2t, fc2_b, etok, ewt, kept, out);
}